// Round 3
// baseline (1682.706 us; speedup 1.0000x reference)
//
#include <hip/hip_runtime.h>

// Problem constants (fixed by setup_inputs)
#define B_    4
#define H_    32
#define W_    32
#define N_    1024      // H*W
#define CIN_  256
#define CHID_ 1024
#define C2_   512

typedef __attribute__((ext_vector_type(8))) short short8b;   // 8 bf16
typedef __attribute__((ext_vector_type(4))) float f32x4;     // MFMA acc

// fp32 -> bf16 (RNE)
__device__ __forceinline__ unsigned int f2bf2(float lo, float hi) {
    unsigned int ul = __float_as_uint(lo);
    unsigned int uh = __float_as_uint(hi);
    ul += 0x7fffu + ((ul >> 16) & 1u);
    uh += 0x7fffu + ((uh >> 16) & 1u);
    return (ul >> 16) | (uh & 0xffff0000u);
}
__device__ __forceinline__ unsigned short f2bf(float f) {
    unsigned int u = __float_as_uint(f);
    u += 0x7fffu + ((u >> 16) & 1u);
    return (unsigned short)(u >> 16);
}

#define ROWP 40   // LDS row pitch in ushorts (80 B): 2-way bank alias = free

// ---------------------------------------------------------------------------
// bf16 MFMA GEMM.  C[m][o] = base + sum_k Avirt[m][k] * B[o][k]
//   base = bias[o] (accflag=0) or C_old (accflag=1)
// B is FRAGMENT-PACKED: for (o,k): dst = ((o16*nk32 + k32)*64 + lane)*8 + (k&7)
//   with lane = (o&15) + ((k>>3)&3)*16  -> a wave's B-frag is one coalesced
//   16B/lane global load, no LDS for B.
// A modes: 0 = bf16 row-major        (samp)
//          1 = fp32 row-major + cvt  (x, h)
//          2 = fp32 + spatial shift  (h for offsets; dacc unused now)
//          3 = bf16 + spatial shift  (daccb for plain convs)
// Tap for shift modes: t = k>>9 (Kc=512 folded in K).
// Block 256 thr = 4 waves (2x2), tile 64x64, wave subtile 32x32, BK=32.
// ---------------------------------------------------------------------------
template<int AMODE, int KS>
__device__ __forceinline__ uint4 loadA_fn(const void* __restrict__ Asrc, int lda,
                                          int am, int ab, int ay, int ax, int k)
{
    const int PAD = KS / 2;
    if constexpr (AMODE == 0) {
        return *(const uint4*)((const unsigned short*)Asrc + (size_t)am * lda + k);
    } else if constexpr (AMODE == 1) {
        const float* p = (const float*)Asrc + (size_t)am * lda + k;
        const float4 v0 = *(const float4*)p;
        const float4 v1 = *(const float4*)(p + 4);
        return make_uint4(f2bf2(v0.x, v0.y), f2bf2(v0.z, v0.w),
                          f2bf2(v1.x, v1.y), f2bf2(v1.z, v1.w));
    } else if constexpr (AMODE == 2) {
        const int t = k >> 9, c = k & 511;
        const int yy = ay + t / KS - PAD, xx = ax + t % KS - PAD;
        if (yy >= 0 && yy < H_ && xx >= 0 && xx < W_) {
            const float* p = (const float*)Asrc
                + (size_t)((ab << 10) | (yy << 5) | xx) * lda + c;
            const float4 v0 = *(const float4*)p;
            const float4 v1 = *(const float4*)(p + 4);
            return make_uint4(f2bf2(v0.x, v0.y), f2bf2(v0.z, v0.w),
                              f2bf2(v1.x, v1.y), f2bf2(v1.z, v1.w));
        }
        return make_uint4(0u, 0u, 0u, 0u);
    } else {  // AMODE 3: bf16 + shift
        const int t = k >> 9, c = k & 511;
        const int yy = ay + t / KS - PAD, xx = ax + t % KS - PAD;
        if (yy >= 0 && yy < H_ && xx >= 0 && xx < W_) {
            return *(const uint4*)((const unsigned short*)Asrc
                + (size_t)((ab << 10) | (yy << 5) | xx) * lda + c);
        }
        return make_uint4(0u, 0u, 0u, 0u);
    }
}

template<int AMODE, int KS>
__global__ __launch_bounds__(256)
void gemm_bf(const void* __restrict__ Asrc, int lda,
             const unsigned short* __restrict__ Bp, int Ktot,
             const float* __restrict__ bias,
             float* __restrict__ C, int ldo, int O, int accflag)
{
    __shared__ unsigned short As[2][64 * ROWP];

    const int tid = threadIdx.x;
    const int m0 = blockIdx.y * 64;
    const int o0 = blockIdx.x * 64;

    // staging role: row = tid>>2 (0..63), k-octet = (tid&3)*8
    const int srow = tid >> 2;
    const int sk8  = (tid & 3) << 3;
    const int am   = m0 + srow;
    const int an = am & (N_ - 1);
    const int ab = am >> 10;
    const int ay = an >> 5, ax = an & 31;

    // compute role
    const int lane = tid & 63;
    const int wid  = tid >> 6;
    const int wr = (wid >> 1) * 32;
    const int wc = (wid & 1) * 32;
    const int l15 = lane & 15;
    const int lk  = (lane >> 4) * 8;

    const int nk32 = Ktot >> 5;
    const unsigned short* bb0 =
        Bp + ((size_t)(((o0 + wc) >> 4) * nk32) * 64 + lane) * 8;
    const unsigned short* bb1 =
        Bp + ((size_t)(((o0 + wc + 16) >> 4) * nk32) * 64 + lane) * 8;

    f32x4 acc[2][2];
#pragma unroll
    for (int i = 0; i < 2; ++i)
#pragma unroll
        for (int j = 0; j < 2; ++j)
            acc[i][j] = (f32x4){0.f, 0.f, 0.f, 0.f};

    // prologue: stage k0 = 0 into buffer 0
    {
        const uint4 v = loadA_fn<AMODE, KS>(Asrc, lda, am, ab, ay, ax, sk8);
        *(uint4*)&As[0][srow * ROWP + sk8] = v;
    }
    __syncthreads();

    int cur = 0;
    for (int k0 = 0; k0 < Ktot; k0 += 32) {
        uint4 nv;
        const bool more = (k0 + 32) < Ktot;
        if (more) nv = loadA_fn<AMODE, KS>(Asrc, lda, am, ab, ay, ax, k0 + 32 + sk8);

        const short8b bf0 = *(const short8b*)(bb0 + (size_t)(k0 >> 5) * 512);
        const short8b bf1 = *(const short8b*)(bb1 + (size_t)(k0 >> 5) * 512);

        const unsigned short* as = As[cur];
        const short8b af0 = *(const short8b*)(as + (wr +      l15) * ROWP + lk);
        const short8b af1 = *(const short8b*)(as + (wr + 16 + l15) * ROWP + lk);

        acc[0][0] = __builtin_amdgcn_mfma_f32_16x16x32_bf16(af0, bf0, acc[0][0], 0, 0, 0);
        acc[0][1] = __builtin_amdgcn_mfma_f32_16x16x32_bf16(af0, bf1, acc[0][1], 0, 0, 0);
        acc[1][0] = __builtin_amdgcn_mfma_f32_16x16x32_bf16(af1, bf0, acc[1][0], 0, 0, 0);
        acc[1][1] = __builtin_amdgcn_mfma_f32_16x16x32_bf16(af1, bf1, acc[1][1], 0, 0, 0);

        if (more) *(uint4*)&As[cur ^ 1][srow * ROWP + sk8] = nv;
        __syncthreads();
        cur ^= 1;
    }

    // epilogue: C/D layout col = lane&15, row = (lane>>4)*4 + r  (verified)
    const int row0 = m0 + wr + (lane >> 4) * 4;
    const int col0 = o0 + wc + l15;
#pragma unroll
    for (int j = 0; j < 2; ++j) {
        const int cc = col0 + j * 16;
        if (cc < O) {
#pragma unroll
            for (int i = 0; i < 2; ++i)
#pragma unroll
                for (int r = 0; r < 4; ++r) {
                    const size_t idx = (size_t)(row0 + i * 16 + r) * ldo + cc;
                    const float base = accflag ? C[idx] : bias[cc];
                    C[idx] = acc[i][j][r] + base;
                }
        }
    }
}

// ---------------------------------------------------------------------------
// Weight fragment-packing.  src w: [O][Kc][KK] (conv, KK>1) or [O][Kc] (KK=1).
// dst row od in [0,Opad), source row o = obase+od (valid if od < Ovalid).
// k in [0,Ktot): t = t0 + (k>>9), c = k&511 (conv) / direct (KK=1).
// ---------------------------------------------------------------------------
__global__ void pack_w(const float* __restrict__ w, unsigned short* __restrict__ dst,
                       int Ovalid, int Opad, int obase, int Kc, int KK, int t0, int Ktot)
{
    const int gid = blockIdx.x * blockDim.x + threadIdx.x;
    if (gid >= Opad * Ktot) return;
    const int k  = gid % Ktot;
    const int od = gid / Ktot;
    float v = 0.f;
    if (od < Ovalid) {
        const size_t o = obase + od;
        if (KK == 1) {
            v = w[o * Kc + k];
        } else {
            const int t = t0 + (k >> 9);
            const int c = k & 511;
            v = w[(o * Kc + c) * KK + t];
        }
    }
    const int o16 = od >> 4, l = od & 15, k32 = k >> 5;
    const size_t di = ((size_t)(o16 * (Ktot >> 5) + k32) * 64
                       + (l + ((k >> 3) & 3) * 16)) * 8 + (k & 7);
    dst[di] = f2bf(v);
}

// ---------------------------------------------------------------------------
// Bilinear coefficients per (token m, tap t)  [verified]
// ---------------------------------------------------------------------------
template<int KS>
__global__ void coeff_kernel(const float* __restrict__ offb, int KK2,
                             int4* __restrict__ cidx, float4* __restrict__ cwt)
{
    const int KK = KS * KS, PAD = KS / 2;
    const int gid = blockIdx.x * blockDim.x + threadIdx.x;
    if (gid >= B_ * N_ * KK) return;
    const int t = gid % KK;
    const int n = (gid / KK) & (N_ - 1);
    const int b = gid / (KK * N_);
    const int mtok = b * N_ + n;

    const float dy = offb[(size_t)mtok * KK2 + 2 * t];
    const float dx = offb[(size_t)mtok * KK2 + 2 * t + 1];
    const int y = n >> 5, x = n & 31;
    const float py = (float)(y - PAD + t / KS) + dy;
    const float px = (float)(x - PAD + t % KS) + dx;
    const float y0f = floorf(py), x0f = floorf(px);
    const float fy = py - y0f, fx = px - x0f;
    const int y0 = (int)y0f, x0 = (int)x0f;

    int idx[4]; float wt[4];
    const int   yy[4] = {y0, y0, y0 + 1, y0 + 1};
    const int   xx[4] = {x0, x0 + 1, x0, x0 + 1};
    const float ww[4] = {(1.f - fy) * (1.f - fx), (1.f - fy) * fx,
                         fy * (1.f - fx),         fy * fx};
#pragma unroll
    for (int r = 0; r < 4; ++r) {
        const bool v = (yy[r] >= 0 && yy[r] < H_ && xx[r] >= 0 && xx[r] < W_);
        const int yc = min(max(yy[r], 0), H_ - 1);
        const int xc = min(max(xx[r], 0), W_ - 1);
        idx[r] = b * N_ + yc * W_ + xc;
        wt[r] = v ? ww[r] : 0.f;
    }
    cidx[(size_t)mtok * KK + t] = make_int4(idx[0], idx[1], idx[2], idx[3]);
    cwt[(size_t)mtok * KK + t] = make_float4(wt[0], wt[1], wt[2], wt[3]);
}

// ---------------------------------------------------------------------------
// Materialize bilinear-sampled activations for a chunk of G taps (bf16).
// samp[m][(t-t0)*512 + c] = bf16( sum_r cw[r] * h[ci[r]][c] )
// One wave handles one (m, tap): 64 threads x 8 channels.
// ---------------------------------------------------------------------------
__global__ void samp_gen(const float* __restrict__ hsrc, int lda,
                         const int4* __restrict__ cidx, const float4* __restrict__ cwt,
                         int KK, int t0, int G, unsigned short* __restrict__ samp)
{
    const int gid = blockIdx.x * blockDim.x + threadIdx.x;
    if (gid >= B_ * N_ * G * 64) return;
    const int c8 = gid & 63;
    const int tg = (gid >> 6) % G;
    const int m  = gid / (64 * G);
    const int t  = t0 + tg;

    const int4   ci = cidx[(size_t)m * KK + t];
    const float4 cw = cwt [(size_t)m * KK + t];
    const int c0 = c8 << 3;
    const float* p0 = hsrc + (size_t)ci.x * lda + c0;
    const float* p1 = hsrc + (size_t)ci.y * lda + c0;
    const float* p2 = hsrc + (size_t)ci.z * lda + c0;
    const float* p3 = hsrc + (size_t)ci.w * lda + c0;

    float r[8];
#pragma unroll
    for (int q = 0; q < 2; ++q) {
        const float4 a0 = *(const float4*)(p0 + 4 * q);
        const float4 a1 = *(const float4*)(p1 + 4 * q);
        const float4 a2 = *(const float4*)(p2 + 4 * q);
        const float4 a3 = *(const float4*)(p3 + 4 * q);
        r[4*q+0] = cw.x*a0.x + cw.y*a1.x + cw.z*a2.x + cw.w*a3.x;
        r[4*q+1] = cw.x*a0.y + cw.y*a1.y + cw.z*a2.y + cw.w*a3.y;
        r[4*q+2] = cw.x*a0.z + cw.y*a1.z + cw.z*a2.z + cw.w*a3.z;
        r[4*q+3] = cw.x*a0.w + cw.y*a1.w + cw.z*a2.w + cw.w*a3.w;
    }
    const uint4 o = make_uint4(f2bf2(r[0], r[1]), f2bf2(r[2], r[3]),
                               f2bf2(r[4], r[5]), f2bf2(r[6], r[7]));
    *(uint4*)&samp[(size_t)m * (G * 512) + tg * 512 + c0] = o;
}

// ---------------------------------------------------------------------------
// fp32 -> bf16 bulk cast (8 elements/thread)
// ---------------------------------------------------------------------------
__global__ void cast_bf8(const float* __restrict__ src,
                         unsigned short* __restrict__ dst, int n8)
{
    const int g = blockIdx.x * blockDim.x + threadIdx.x;
    if (g >= n8) return;
    const float4 v0 = *(const float4*)(src + (size_t)g * 8);
    const float4 v1 = *(const float4*)(src + (size_t)g * 8 + 4);
    *(uint4*)&dst[(size_t)g * 8] = make_uint4(f2bf2(v0.x, v0.y), f2bf2(v0.z, v0.w),
                                              f2bf2(v1.x, v1.y), f2bf2(v1.z, v1.w));
}

// ---------------------------------------------------------------------------
// LayerNorm + exact GELU  [verified]
// ---------------------------------------------------------------------------
__global__ __launch_bounds__(256)
void ln_gelu(float* __restrict__ ytok, const float* __restrict__ g,
             const float* __restrict__ bt)
{
    const int t = blockIdx.x;
    const int tid = threadIdx.x;
    float* row = ytok + (size_t)t * CHID_;

    float4 v = *(const float4*)&row[tid << 2];
    __shared__ float red[4];

    float s = v.x + v.y + v.z + v.w;
#pragma unroll
    for (int o = 32; o > 0; o >>= 1) s += __shfl_down(s, o, 64);
    if ((tid & 63) == 0) red[tid >> 6] = s;
    __syncthreads();
    const float mean = (red[0] + red[1] + red[2] + red[3]) * (1.f / CHID_);

    const float d0 = v.x - mean, d1 = v.y - mean, d2 = v.z - mean, d3 = v.w - mean;
    float q = d0 * d0 + d1 * d1 + d2 * d2 + d3 * d3;
#pragma unroll
    for (int o = 32; o > 0; o >>= 1) q += __shfl_down(q, o, 64);
    __syncthreads();
    if ((tid & 63) == 0) red[tid >> 6] = q;
    __syncthreads();
    const float var = (red[0] + red[1] + red[2] + red[3]) * (1.f / CHID_);
    const float rstd = rsqrtf(var + 1e-5f);

    const float4 gv = *(const float4*)&g[tid << 2];
    const float4 bv = *(const float4*)&bt[tid << 2];
    float o0 = d0 * rstd * gv.x + bv.x;
    float o1 = d1 * rstd * gv.y + bv.y;
    float o2 = d2 * rstd * gv.z + bv.z;
    float o3 = d3 * rstd * gv.w + bv.w;
    o0 = 0.5f * o0 * (1.f + erff(o0 * 0.70710678118654752f));
    o1 = 0.5f * o1 * (1.f + erff(o1 * 0.70710678118654752f));
    o2 = 0.5f * o2 * (1.f + erff(o2 * 0.70710678118654752f));
    o3 = 0.5f * o3 * (1.f + erff(o3 * 0.70710678118654752f));
    *(float4*)&row[tid << 2] = make_float4(o0, o1, o2, o3);
}

// ---------------------------------------------------------------------------
extern "C" void kernel_launch(void* const* d_in, const int* in_sizes, int n_in,
                              void* d_out, int out_size, void* d_ws, size_t ws_size,
                              hipStream_t stream) {
    const float* x       = (const float*)d_in[0];
    const float* fc1_w   = (const float*)d_in[3];
    const float* fc1_b   = (const float*)d_in[4];
    const float* off3_w  = (const float*)d_in[5];
    const float* off3_b  = (const float*)d_in[6];
    const float* conv3_w = (const float*)d_in[7];
    const float* conv3_b = (const float*)d_in[8];
    const float* off5_w  = (const float*)d_in[9];
    const float* off5_b  = (const float*)d_in[10];
    const float* conv5_w = (const float*)d_in[11];
    const float* conv5_b = (const float*)d_in[12];
    const float* ln_g    = (const float*)d_in[13];
    const float* ln_b    = (const float*)d_in[14];
    const float* fc2_w   = (const float*)d_in[15];
    const float* fc2_b   = (const float*)d_in[16];
    float* out = (float*)d_out;   // fp32 output

    // Workspace layout (max concurrent use 50.50 MB < 51.2 MB verified floor)
    char* ws = (char*)d_ws;
    float*          h     = (float*)(ws);              // 16,777,216 [4096][1024]
    float*          dacc  = (float*)(ws + 16777216);   //  8,388,608 [4096][512]
    float*          offb  = (float*)(ws + 25165824);   //    819,200 [4096][<=50]
    int4*           cidx3 = (int4*)  (ws + 25985024);  //    589,824
    float4*         cwt3  = (float4*)(ws + 26574848);  //    589,824
    int4*           cidx5 = (int4*)  (ws + 27164672);  //  1,638,400
    float4*         cwt5  = (float4*)(ws + 28803072);  //  1,638,400
    unsigned short* fc1wb = (unsigned short*)(ws + 30441472);  // 524,288 [1024p][256]
    unsigned short* fc2wb = (unsigned short*)(ws + 30965760);  // 524,288 [256p][1024]
    unsigned short* off3wb= (unsigned short*)(ws + 31490048);  // 589,824 [64p][4608]
    unsigned short* off5wb= (unsigned short*)(ws + 32079872);  // 1,638,400 [64p][12800]
    // wchunk aliases the off3wb/off5wb region (free after both off-gemms):
    unsigned short* wchunk = (unsigned short*)(ws + 31490048); // <=2,097,152 [512p][G*512]
    // BIG region [33718272, 50495488): samp (deform phase) OR daccb+convhalf (plain phase)
    unsigned short* samp     = (unsigned short*)(ws + 33718272); // <=16,777,216
    unsigned short* daccb    = (unsigned short*)(ws + 33718272); //   4,194,304
    unsigned short* convhalf = (unsigned short*)(ws + 37912576); // <=6,553,600

    const dim3 TB(256);
    const int MT = (B_ * N_) / 64;   // 64 m-tiles

    // ---- weight fragment-packs (activation-independent) ----
    pack_w<<<(1024*256 + 255)/256, TB, 0, stream>>>(fc1_w, fc1wb, 1024, 1024, 0, 256, 1, 0, 256);
    pack_w<<<(256*1024 + 255)/256, TB, 0, stream>>>(fc2_w, fc2wb, 256, 256, 0, 1024, 1, 0, 1024);
    pack_w<<<(64*4608  + 255)/256, TB, 0, stream>>>(off3_w, off3wb, 18, 64, 0, 512, 9, 0, 4608);
    pack_w<<<(64*12800 + 255)/256, TB, 0, stream>>>(off5_w, off5wb, 50, 64, 0, 512, 25, 0, 12800);

    // ---- fc1 ----
    gemm_bf<1,1><<<dim3(16, MT), TB, 0, stream>>>(
        x, CIN_, fc1wb, 256, fc1_b, h, CHID_, CHID_, 0);

    // ---- offset convs + coeffs (both branches; frees offw region for wchunk) ----
    gemm_bf<2,3><<<dim3(1, MT), TB, 0, stream>>>(
        h, CHID_, off3wb, 4608, off3_b, offb, 18, 18, 0);
    coeff_kernel<3><<<(B_*N_*9 + 255)/256, TB, 0, stream>>>(offb, 18, cidx3, cwt3);
    gemm_bf<2,5><<<dim3(1, MT), TB, 0, stream>>>(
        h + C2_, CHID_, off5wb, 12800, off5_b, offb, 50, 50, 0);
    coeff_kernel<5><<<(B_*N_*25 + 255)/256, TB, 0, stream>>>(offb, 50, cidx5, cwt5);

    // ---- branch 1 (k=3): deform chunks {3,3,3} -> dacc ----
    {
        const int t0s[3] = {0, 3, 6}, Gs[3] = {3, 3, 3};
        for (int ch = 0; ch < 3; ++ch) {
            const int t0 = t0s[ch], G = Gs[ch], Kt = G * 512;
            samp_gen<<<(B_*N_*G*64 + 255)/256, TB, 0, stream>>>(
                h, CHID_, cidx3, cwt3, 9, t0, G, samp);
            pack_w<<<(512*Kt + 255)/256, TB, 0, stream>>>(
                conv3_w, wchunk, 512, 512, 0, 512, 9, t0, Kt);
            gemm_bf<0,1><<<dim3(8, MT), TB, 0, stream>>>(
                samp, Kt, wchunk, Kt, conv3_b, dacc, C2_, C2_, ch > 0);
        }
    }
    // ---- branch 1 plain conv: dacc -> h[:, :512] ----
    cast_bf8<<<(B_*N_*C2_/8 + 255)/256, TB, 0, stream>>>(dacc, daccb, B_*N_*C2_/8);
    for (int hf = 0; hf < 2; ++hf) {
        pack_w<<<(256*4608 + 255)/256, TB, 0, stream>>>(
            conv3_w, convhalf, 256, 256, hf*256, 512, 9, 0, 4608);
        gemm_bf<3,3><<<dim3(4, MT), TB, 0, stream>>>(
            daccb, C2_, convhalf, 4608, conv3_b + hf*256, h + hf*256, CHID_, 256, 0);
    }

    // ---- branch 2 (k=5): deform chunks {4,4,4,4,4,4,1} -> dacc ----
    {
        for (int ch = 0; ch < 7; ++ch) {
            const int t0 = ch * 4;
            const int G  = (ch == 6) ? 1 : 4;
            const int Kt = G * 512;
            samp_gen<<<(B_*N_*G*64 + 255)/256, TB, 0, stream>>>(
                h + C2_, CHID_, cidx5, cwt5, 25, t0, G, samp);
            pack_w<<<(512*Kt + 255)/256, TB, 0, stream>>>(
                conv5_w, wchunk, 512, 512, 0, 512, 25, t0, Kt);
            gemm_bf<0,1><<<dim3(8, MT), TB, 0, stream>>>(
                samp, Kt, wchunk, Kt, conv5_b, dacc, C2_, C2_, ch > 0);
        }
    }
    // ---- branch 2 plain conv: dacc -> h[:, 512:] ----
    cast_bf8<<<(B_*N_*C2_/8 + 255)/256, TB, 0, stream>>>(dacc, daccb, B_*N_*C2_/8);
    for (int hf = 0; hf < 2; ++hf) {
        pack_w<<<(256*12800 + 255)/256, TB, 0, stream>>>(
            conv5_w, convhalf, 256, 256, hf*256, 512, 25, 0, 12800);
        gemm_bf<3,5><<<dim3(4, MT), TB, 0, stream>>>(
            daccb, C2_, convhalf, 12800, conv5_b + hf*256, h + C2_ + hf*256, CHID_, 256, 0);
    }

    // ---- LN + GELU, then fc2 -> fp32 out ----
    ln_gelu<<<B_*N_, TB, 0, stream>>>(h, ln_g, ln_b);
    gemm_bf<1,1><<<dim3(4, MT), TB, 0, stream>>>(
        h, CHID_, fc2wb, 1024, fc2_b, out, CIN_, CIN_, 0);
}

// Round 4
// 930.989 us; speedup vs baseline: 1.8074x; 1.8074x over previous
//
#include <hip/hip_runtime.h>

// Problem constants (fixed by setup_inputs)
#define B_    4
#define H_    32
#define W_    32
#define N_    1024      // H*W
#define CIN_  256
#define CHID_ 1024
#define C2_   512

typedef __attribute__((ext_vector_type(8))) short short8b;   // 8 bf16
typedef __attribute__((ext_vector_type(4))) float f32x4;     // MFMA acc

// fp32 -> bf16 (RNE)
__device__ __forceinline__ unsigned int f2bf2(float lo, float hi) {
    unsigned int ul = __float_as_uint(lo);
    unsigned int uh = __float_as_uint(hi);
    ul += 0x7fffu + ((ul >> 16) & 1u);
    uh += 0x7fffu + ((uh >> 16) & 1u);
    return (ul >> 16) | (uh & 0xffff0000u);
}
__device__ __forceinline__ unsigned short f2bf(float f) {
    unsigned int u = __float_as_uint(f);
    u += 0x7fffu + ((u >> 16) & 1u);
    return (unsigned short)(u >> 16);
}

#define ROWP 40   // LDS row pitch (ushorts): 80B stride -> 2-way alias = free

// ---------------------------------------------------------------------------
// A-operand staging loads (8 bf16 = one uint4), k is global k index.
// AMODE 0: fp32 row-major + cvt            (x, h for fc1/fc2)
// AMODE 1: fp32 spatial-shift + cvt        (h for offset convs)   t = k>>9
// AMODE 2: fp32 bilinear gather + cvt      (h for deform convs)   t = k>>9
// AMODE 3: bf16 spatial-shift              (daccb for plain convs) t = k>>9
// ---------------------------------------------------------------------------
template<int AMODE, int KS>
__device__ __forceinline__ uint4 loadA(const void* __restrict__ Asrc, int lda,
                                       int am, int ab, int ay, int ax, int k,
                                       const int4* __restrict__ cidx,
                                       const float4* __restrict__ cwt, int KK)
{
    const int PAD = KS / 2;
    if constexpr (AMODE == 0) {
        const float* p = (const float*)Asrc + (size_t)am * lda + k;
        const float4 v0 = *(const float4*)p;
        const float4 v1 = *(const float4*)(p + 4);
        return make_uint4(f2bf2(v0.x, v0.y), f2bf2(v0.z, v0.w),
                          f2bf2(v1.x, v1.y), f2bf2(v1.z, v1.w));
    } else if constexpr (AMODE == 1) {
        const int t = k >> 9, c = k & 511;
        const int yy = ay + t / KS - PAD, xx = ax + t % KS - PAD;
        if (yy >= 0 && yy < H_ && xx >= 0 && xx < W_) {
            const float* p = (const float*)Asrc
                + (size_t)((ab << 10) | (yy << 5) | xx) * lda + c;
            const float4 v0 = *(const float4*)p;
            const float4 v1 = *(const float4*)(p + 4);
            return make_uint4(f2bf2(v0.x, v0.y), f2bf2(v0.z, v0.w),
                              f2bf2(v1.x, v1.y), f2bf2(v1.z, v1.w));
        }
        return make_uint4(0u, 0u, 0u, 0u);
    } else if constexpr (AMODE == 2) {
        const int t = k >> 9, c = k & 511;
        const int4   ci = cidx[(size_t)am * KK + t];
        const float4 cw = cwt [(size_t)am * KK + t];
        const float* p0 = (const float*)Asrc + (size_t)ci.x * lda + c;
        const float* p1 = (const float*)Asrc + (size_t)ci.y * lda + c;
        const float* p2 = (const float*)Asrc + (size_t)ci.z * lda + c;
        const float* p3 = (const float*)Asrc + (size_t)ci.w * lda + c;
        float r[8];
#pragma unroll
        for (int q = 0; q < 2; ++q) {
            const float4 a0 = *(const float4*)(p0 + 4 * q);
            const float4 a1 = *(const float4*)(p1 + 4 * q);
            const float4 a2 = *(const float4*)(p2 + 4 * q);
            const float4 a3 = *(const float4*)(p3 + 4 * q);
            r[4*q+0] = cw.x*a0.x + cw.y*a1.x + cw.z*a2.x + cw.w*a3.x;
            r[4*q+1] = cw.x*a0.y + cw.y*a1.y + cw.z*a2.y + cw.w*a3.y;
            r[4*q+2] = cw.x*a0.z + cw.y*a1.z + cw.z*a2.z + cw.w*a3.z;
            r[4*q+3] = cw.x*a0.w + cw.y*a1.w + cw.z*a2.w + cw.w*a3.w;
        }
        return make_uint4(f2bf2(r[0], r[1]), f2bf2(r[2], r[3]),
                          f2bf2(r[4], r[5]), f2bf2(r[6], r[7]));
    } else {  // AMODE 3
        const int t = k >> 9, c = k & 511;
        const int yy = ay + t / KS - PAD, xx = ax + t % KS - PAD;
        if (yy >= 0 && yy < H_ && xx >= 0 && xx < W_) {
            return *(const uint4*)((const unsigned short*)Asrc
                + (size_t)((ab << 10) | (yy << 5) | xx) * lda + c);
        }
        return make_uint4(0u, 0u, 0u, 0u);
    }
}

// ---------------------------------------------------------------------------
// bf16 MFMA GEMM, tile 64x128, 8 waves (2 row x 4 col), BK=64, A in LDS
// (double-buffered, 1 barrier/step), B fragment-packed from global.
// OUTMODE 0: fp32 + bias    1: bf16 + bias    2: fp32 K-split partial (no bias)
// Grid: (O/128 ceil, M/64, Ksplits).  Ksplit multiple of 64.
// ---------------------------------------------------------------------------
template<int AMODE, int KS, int OUTMODE>
__global__ __launch_bounds__(512, 2)
void gemm2(const void* __restrict__ Asrc, int lda,
           const unsigned short* __restrict__ Bp, int Ktot, int Ksplit,
           const float* __restrict__ bias, void* __restrict__ Cout, int ldo, int O,
           const int4* __restrict__ cidx, const float4* __restrict__ cwt, int KK)
{
    __shared__ unsigned short As[2][2][64 * ROWP];

    const int tid = threadIdx.x;
    const int m0 = blockIdx.y * 64;
    const int o0 = blockIdx.x * 128;
    const int kbeg = blockIdx.z * Ksplit;
    const int kend = kbeg + Ksplit;

    // staging role: row = tid>>3 (0..63), k-octet = (tid&7)*8 (0..56)
    const int srow = tid >> 3;
    const int sk8  = (tid & 7) << 3;
    const int am = m0 + srow;
    const int an = am & (N_ - 1);
    const int ab = am >> 10;
    const int ay = an >> 5, ax = an & 31;

    // compute role: 8 waves, 2x4; wave subtile 32x32
    const int lane = tid & 63;
    const int wid  = tid >> 6;
    const int wr = (wid >> 2) * 32;
    const int wc = (wid & 3) * 32;
    const int l15 = lane & 15;
    const int lk  = (lane >> 4) * 8;

    const int nk32 = Ktot >> 5;
    const unsigned short* bb0 =
        Bp + ((size_t)(((o0 + wc) >> 4) * nk32) * 64 + lane) * 8;
    const unsigned short* bb1 =
        Bp + ((size_t)(((o0 + wc + 16) >> 4) * nk32) * 64 + lane) * 8;

    f32x4 acc[2][2];
#pragma unroll
    for (int i = 0; i < 2; ++i)
#pragma unroll
        for (int j = 0; j < 2; ++j)
            acc[i][j] = (f32x4){0.f, 0.f, 0.f, 0.f};

    // prologue: stage first BK64
    {
        const uint4 v = loadA<AMODE, KS>(Asrc, lda, am, ab, ay, ax,
                                         kbeg + sk8, cidx, cwt, KK);
        *(uint4*)&As[0][sk8 >> 5][srow * ROWP + (sk8 & 31)] = v;
    }
    __syncthreads();

    int cur = 0;
    for (int k0 = kbeg; k0 < kend; k0 += 64) {
        const int q = k0 >> 5;
        // issue B loads for current step (independent of LDS/barrier)
        const short8b b00 = *(const short8b*)(bb0 + (size_t)(q    ) * 512);
        const short8b b01 = *(const short8b*)(bb0 + (size_t)(q + 1) * 512);
        const short8b b10 = *(const short8b*)(bb1 + (size_t)(q    ) * 512);
        const short8b b11 = *(const short8b*)(bb1 + (size_t)(q + 1) * 512);

        // gather/stage next step into regs (covers B latency with VALU)
        const bool more = (k0 + 64) < kend;
        uint4 nv;
        if (more) nv = loadA<AMODE, KS>(Asrc, lda, am, ab, ay, ax,
                                        k0 + 64 + sk8, cidx, cwt, KK);

        // fragments + MFMA for current step
        const unsigned short* a0 = As[cur][0];
        const unsigned short* a1 = As[cur][1];
        const short8b af00 = *(const short8b*)(a0 + (wr +      l15) * ROWP + lk);
        const short8b af01 = *(const short8b*)(a0 + (wr + 16 + l15) * ROWP + lk);
        const short8b af10 = *(const short8b*)(a1 + (wr +      l15) * ROWP + lk);
        const short8b af11 = *(const short8b*)(a1 + (wr + 16 + l15) * ROWP + lk);

        acc[0][0] = __builtin_amdgcn_mfma_f32_16x16x32_bf16(af00, b00, acc[0][0], 0, 0, 0);
        acc[0][1] = __builtin_amdgcn_mfma_f32_16x16x32_bf16(af00, b10, acc[0][1], 0, 0, 0);
        acc[1][0] = __builtin_amdgcn_mfma_f32_16x16x32_bf16(af01, b00, acc[1][0], 0, 0, 0);
        acc[1][1] = __builtin_amdgcn_mfma_f32_16x16x32_bf16(af01, b10, acc[1][1], 0, 0, 0);
        acc[0][0] = __builtin_amdgcn_mfma_f32_16x16x32_bf16(af10, b01, acc[0][0], 0, 0, 0);
        acc[0][1] = __builtin_amdgcn_mfma_f32_16x16x32_bf16(af10, b11, acc[0][1], 0, 0, 0);
        acc[1][0] = __builtin_amdgcn_mfma_f32_16x16x32_bf16(af11, b01, acc[1][0], 0, 0, 0);
        acc[1][1] = __builtin_amdgcn_mfma_f32_16x16x32_bf16(af11, b11, acc[1][1], 0, 0, 0);

        if (more) *(uint4*)&As[cur ^ 1][sk8 >> 5][srow * ROWP + (sk8 & 31)] = nv;
        __syncthreads();
        cur ^= 1;
    }

    // epilogue: C/D layout col = lane&15, row = (lane>>4)*4 + r  (verified)
    const int row0 = m0 + wr + (lane >> 4) * 4;
    const int col0 = o0 + wc + l15;
#pragma unroll
    for (int j = 0; j < 2; ++j) {
        const int cc = col0 + j * 16;
        if (cc < O) {
#pragma unroll
            for (int i = 0; i < 2; ++i)
#pragma unroll
                for (int r = 0; r < 4; ++r) {
                    const int row = row0 + i * 16 + r;
                    if constexpr (OUTMODE == 0) {
                        ((float*)Cout)[(size_t)row * ldo + cc] = acc[i][j][r] + bias[cc];
                    } else if constexpr (OUTMODE == 1) {
                        ((unsigned short*)Cout)[(size_t)row * ldo + cc] =
                            f2bf(acc[i][j][r] + bias[cc]);
                    } else {
                        ((float*)Cout)[((size_t)blockIdx.z * (B_ * N_) + row) * ldo + cc] =
                            acc[i][j][r];
                    }
                }
        }
    }
}

// ---------------------------------------------------------------------------
// Weight fragment-packing (verified R3).  src: [O][Kc][KK] (KK>1) or [O][Kc].
// dst frag: ((o16*nk32 + k32)*64 + (o&15) + ((k>>3)&3)*16)*8 + (k&7)
// ---------------------------------------------------------------------------
__global__ void pack_w(const float* __restrict__ w, unsigned short* __restrict__ dst,
                       int Ovalid, int Opad, int obase, int Kc, int KK, int t0, int Ktot)
{
    const int gid = blockIdx.x * blockDim.x + threadIdx.x;
    if (gid >= Opad * Ktot) return;
    const int k  = gid % Ktot;
    const int od = gid / Ktot;
    float v = 0.f;
    if (od < Ovalid) {
        const size_t o = obase + od;
        if (KK == 1) {
            v = w[o * Kc + k];
        } else {
            const int t = t0 + (k >> 9);
            const int c = k & 511;
            v = w[(o * Kc + c) * KK + t];
        }
    }
    const int o16 = od >> 4, l = od & 15, k32 = k >> 5;
    const size_t di = ((size_t)(o16 * (Ktot >> 5) + k32) * 64
                       + (l + ((k >> 3) & 3) * 16)) * 8 + (k & 7);
    dst[di] = f2bf(v);
}

// ---------------------------------------------------------------------------
// Bilinear coefficients; offsets come as 4 K-split partials + bias.
// offp layout: [4][B_*N_][64], dy at col 2t, dx at col 2t+1.
// ---------------------------------------------------------------------------
template<int KS>
__global__ void coeff_kernel(const float* __restrict__ offp,
                             const float* __restrict__ ob,
                             int4* __restrict__ cidx, float4* __restrict__ cwt)
{
    const int KK = KS * KS, PAD = KS / 2;
    const int gid = blockIdx.x * blockDim.x + threadIdx.x;
    if (gid >= B_ * N_ * KK) return;
    const int t = gid % KK;
    const int n = (gid / KK) & (N_ - 1);
    const int b = gid / (KK * N_);
    const int mtok = b * N_ + n;

    const int SL = B_ * N_ * 64;
    float dy = ob[2 * t],     dx = ob[2 * t + 1];
#pragma unroll
    for (int s = 0; s < 4; ++s) {
        dy += offp[(size_t)s * SL + (size_t)mtok * 64 + 2 * t];
        dx += offp[(size_t)s * SL + (size_t)mtok * 64 + 2 * t + 1];
    }

    const int y = n >> 5, x = n & 31;
    const float py = (float)(y - PAD + t / KS) + dy;
    const float px = (float)(x - PAD + t % KS) + dx;
    const float y0f = floorf(py), x0f = floorf(px);
    const float fy = py - y0f, fx = px - x0f;
    const int y0 = (int)y0f, x0 = (int)x0f;

    int idx[4]; float wt[4];
    const int   yy[4] = {y0, y0, y0 + 1, y0 + 1};
    const int   xx[4] = {x0, x0 + 1, x0, x0 + 1};
    const float ww[4] = {(1.f - fy) * (1.f - fx), (1.f - fy) * fx,
                         fy * (1.f - fx),         fy * fx};
#pragma unroll
    for (int r = 0; r < 4; ++r) {
        const bool v = (yy[r] >= 0 && yy[r] < H_ && xx[r] >= 0 && xx[r] < W_);
        const int yc = min(max(yy[r], 0), H_ - 1);
        const int xc = min(max(xx[r], 0), W_ - 1);
        idx[r] = b * N_ + yc * W_ + xc;
        wt[r] = v ? ww[r] : 0.f;
    }
    cidx[(size_t)mtok * KK + t] = make_int4(idx[0], idx[1], idx[2], idx[3]);
    cwt[(size_t)mtok * KK + t] = make_float4(wt[0], wt[1], wt[2], wt[3]);
}

// ---------------------------------------------------------------------------
// LayerNorm + exact GELU  (verified)
// ---------------------------------------------------------------------------
__global__ __launch_bounds__(256)
void ln_gelu(float* __restrict__ ytok, const float* __restrict__ g,
             const float* __restrict__ bt)
{
    const int t = blockIdx.x;
    const int tid = threadIdx.x;
    float* row = ytok + (size_t)t * CHID_;

    float4 v = *(const float4*)&row[tid << 2];
    __shared__ float red[4];

    float s = v.x + v.y + v.z + v.w;
#pragma unroll
    for (int o = 32; o > 0; o >>= 1) s += __shfl_down(s, o, 64);
    if ((tid & 63) == 0) red[tid >> 6] = s;
    __syncthreads();
    const float mean = (red[0] + red[1] + red[2] + red[3]) * (1.f / CHID_);

    const float d0 = v.x - mean, d1 = v.y - mean, d2 = v.z - mean, d3 = v.w - mean;
    float q = d0 * d0 + d1 * d1 + d2 * d2 + d3 * d3;
#pragma unroll
    for (int o = 32; o > 0; o >>= 1) q += __shfl_down(q, o, 64);
    __syncthreads();
    if ((tid & 63) == 0) red[tid >> 6] = q;
    __syncthreads();
    const float var = (red[0] + red[1] + red[2] + red[3]) * (1.f / CHID_);
    const float rstd = rsqrtf(var + 1e-5f);

    const float4 gv = *(const float4*)&g[tid << 2];
    const float4 bv = *(const float4*)&bt[tid << 2];
    float o0 = d0 * rstd * gv.x + bv.x;
    float o1 = d1 * rstd * gv.y + bv.y;
    float o2 = d2 * rstd * gv.z + bv.z;
    float o3 = d3 * rstd * gv.w + bv.w;
    o0 = 0.5f * o0 * (1.f + erff(o0 * 0.70710678118654752f));
    o1 = 0.5f * o1 * (1.f + erff(o1 * 0.70710678118654752f));
    o2 = 0.5f * o2 * (1.f + erff(o2 * 0.70710678118654752f));
    o3 = 0.5f * o3 * (1.f + erff(o3 * 0.70710678118654752f));
    *(float4*)&row[tid << 2] = make_float4(o0, o1, o2, o3);
}

// ---------------------------------------------------------------------------
extern "C" void kernel_launch(void* const* d_in, const int* in_sizes, int n_in,
                              void* d_out, int out_size, void* d_ws, size_t ws_size,
                              hipStream_t stream) {
    const float* x       = (const float*)d_in[0];
    const float* fc1_w   = (const float*)d_in[3];
    const float* fc1_b   = (const float*)d_in[4];
    const float* off3_w  = (const float*)d_in[5];
    const float* off3_b  = (const float*)d_in[6];
    const float* conv3_w = (const float*)d_in[7];
    const float* conv3_b = (const float*)d_in[8];
    const float* off5_w  = (const float*)d_in[9];
    const float* off5_b  = (const float*)d_in[10];
    const float* conv5_w = (const float*)d_in[11];
    const float* conv5_b = (const float*)d_in[12];
    const float* ln_g    = (const float*)d_in[13];
    const float* ln_b    = (const float*)d_in[14];
    const float* fc2_w   = (const float*)d_in[15];
    const float* fc2_b   = (const float*)d_in[16];
    float* out = (float*)d_out;

    // Workspace layout (50.73 MB < 51.2 MB verified floor)
    char* ws = (char*)d_ws;
    float*          h      = (float*)(ws);               // 16,777,216 [4096][1024]
    float*          offp   = (float*)(ws + 16777216);    //  4,194,304 [4][4096][64]
    int4*           cidx3  = (int4*)  (ws + 20971520);   //    589,824
    float4*         cwt3   = (float4*)(ws + 21561344);   //    589,824
    int4*           cidx5  = (int4*)  (ws + 22151168);   //  1,638,400
    float4*         cwt5   = (float4*)(ws + 23789568);   //  1,638,400
    unsigned short* daccb  = (unsigned short*)(ws + 25427968); // 4,194,304 [4096][512]
    unsigned short* fc1wb  = (unsigned short*)(ws + 29622272); //   524,288
    unsigned short* fc2wb  = (unsigned short*)(ws + 30146560); //   524,288
    unsigned short* off3wb = (unsigned short*)(ws + 30670848); //   589,824 [64p][4608]
    unsigned short* off5wb = (unsigned short*)(ws + 31260672); // 1,638,400 [64p][12800]
    unsigned short* conv3wb= (unsigned short*)(ws + 32899072); // 4,718,592 [512][4608]
    unsigned short* conv5wb= (unsigned short*)(ws + 37617664); // 13,107,200 [512][12800]

    const dim3 TB(256);
    const dim3 TG(512);
    const int MT = (B_ * N_) / 64;   // 64 m-tiles

    // ---- weight fragment-packs ----
    pack_w<<<(1024*256  + 255)/256, TB, 0, stream>>>(fc1_w,  fc1wb,  1024, 1024, 0, 256, 1, 0, 256);
    pack_w<<<(256*1024  + 255)/256, TB, 0, stream>>>(fc2_w,  fc2wb,  256,  256,  0, 1024, 1, 0, 1024);
    pack_w<<<(64*4608   + 255)/256, TB, 0, stream>>>(off3_w, off3wb, 18,   64,   0, 512, 9, 0, 4608);
    pack_w<<<(64*12800  + 255)/256, TB, 0, stream>>>(off5_w, off5wb, 50,   64,   0, 512, 25, 0, 12800);
    pack_w<<<(512*4608  + 255)/256, TB, 0, stream>>>(conv3_w, conv3wb, 512, 512, 0, 512, 9, 0, 4608);
    pack_w<<<(512*12800 + 255)/256, TB, 0, stream>>>(conv5_w, conv5wb, 512, 512, 0, 512, 25, 0, 12800);

    // ---- fc1: h = x @ fc1_w^T + b ----
    gemm2<0,1,0><<<dim3(8, MT, 1), TG, 0, stream>>>(
        x, CIN_, fc1wb, 256, 256, fc1_b, h, CHID_, CHID_, nullptr, nullptr, 0);

    // ---- offset convs (K-split x4 partials) + coeffs ----
    gemm2<1,3,2><<<dim3(1, MT, 4), TG, 0, stream>>>(
        h, CHID_, off3wb, 4608, 1152, nullptr, offp, 64, 64, nullptr, nullptr, 0);
    coeff_kernel<3><<<(B_*N_*9 + 255)/256, TB, 0, stream>>>(offp, off3_b, cidx3, cwt3);
    gemm2<1,5,2><<<dim3(1, MT, 4), TG, 0, stream>>>(
        h + C2_, CHID_, off5wb, 12800, 3200, nullptr, offp, 64, 64, nullptr, nullptr, 0);
    coeff_kernel<5><<<(B_*N_*25 + 255)/256, TB, 0, stream>>>(offp, off5_b, cidx5, cwt5);

    // ---- branch 1: deform conv3 (gather, K=4608) -> daccb bf16 ----
    gemm2<2,3,1><<<dim3(4, MT, 1), TG, 0, stream>>>(
        h, CHID_, conv3wb, 4608, 4608, conv3_b, daccb, C2_, C2_, cidx3, cwt3, 9);
    // ---- branch 1: plain conv3 (bf16 shift) -> h[:, :512] fp32 ----
    gemm2<3,3,0><<<dim3(4, MT, 1), TG, 0, stream>>>(
        daccb, C2_, conv3wb, 4608, 4608, conv3_b, h, CHID_, C2_, nullptr, nullptr, 0);

    // ---- branch 2: deform conv5 (gather, K=12800) -> daccb bf16 ----
    gemm2<2,5,1><<<dim3(4, MT, 1), TG, 0, stream>>>(
        h + C2_, CHID_, conv5wb, 12800, 12800, conv5_b, daccb, C2_, C2_, cidx5, cwt5, 25);
    // ---- branch 2: plain conv5 -> h[:, 512:] fp32 ----
    gemm2<3,5,0><<<dim3(4, MT, 1), TG, 0, stream>>>(
        daccb, C2_, conv5wb, 12800, 12800, conv5_b, h + C2_, CHID_, C2_, nullptr, nullptr, 0);

    // ---- LN + GELU, then fc2 -> fp32 out ----
    ln_gelu<<<B_*N_, TB, 0, stream>>>(h, ln_g, ln_b);
    gemm2<0,1,0><<<dim3(2, MT, 1), TG, 0, stream>>>(
        h, CHID_, fc2wb, 1024, 1024, fc2_b, out, CIN_, CIN_, nullptr, nullptr, 0);
}

// Round 5
// 696.054 us; speedup vs baseline: 2.4175x; 1.3375x over previous
//
#include <hip/hip_runtime.h>

// Problem constants (fixed by setup_inputs)
#define B_    4
#define H_    32
#define W_    32
#define N_    1024      // H*W
#define CIN_  256
#define CHID_ 1024
#define C2_   512

typedef __attribute__((ext_vector_type(8))) short short8b;   // 8 bf16
typedef __attribute__((ext_vector_type(4))) float f32x4;     // MFMA acc

// fp32 -> bf16 (RNE)
__device__ __forceinline__ unsigned int f2bf2(float lo, float hi) {
    unsigned int ul = __float_as_uint(lo);
    unsigned int uh = __float_as_uint(hi);
    ul += 0x7fffu + ((ul >> 16) & 1u);
    uh += 0x7fffu + ((uh >> 16) & 1u);
    return (ul >> 16) | (uh & 0xffff0000u);
}
__device__ __forceinline__ unsigned short f2bf(float f) {
    unsigned int u = __float_as_uint(f);
    u += 0x7fffu + ((u >> 16) & 1u);
    return (unsigned short)(u >> 16);
}
// bf16 pair -> f32 (bit tricks: bf16<<16 is the f32 pattern)
__device__ __forceinline__ float bflo(unsigned int u) { return __uint_as_float(u << 16); }
__device__ __forceinline__ float bfhi(unsigned int u) { return __uint_as_float(u & 0xffff0000u); }

#define ROWP 40   // LDS row pitch (ushorts): 80B stride -> 2-way alias = free
#define MFMA_(a, b, c) __builtin_amdgcn_mfma_f32_16x16x32_bf16(a, b, c, 0, 0, 0)

// ---------------------------------------------------------------------------
// bf16 MFMA GEMM, tile 64x128, 8 waves (2r x 4c), BK=64. A staged via LDS
// (double-buffered, 1 barrier/step); B fragment-packed, direct from global,
// register double-buffered (prefetched one step ahead).
// K is structured as taps x CH*64 channels (CH compile-time).
//   AMODE 0: fp32 row-major + cvt  (x for fc1, ytok for fc2); taps = 1
//   AMODE 1: bf16 + spatial shift  (hb for offsets, daccb for plain convs)
//   AMODE 2: bf16 + bilinear gather(hb for deform convs)
// Tap state (pointers/validity/weights) hoisted: recomputed once per tap,
// steps use immediate offsets (s*64 elems).
//   OUTMODE 0: fp32 + bias   1: bf16 + bias   2: fp32 partial slab (z-split)
// Grid: GX>0 -> 1-D grid GX*64, o0=(bid&(GX-1))*128 (XCD-friendly), m0=(bid/GX)*64
//       GX==0 -> (1, 64, Z): o0=0, tap range z*tcnt..+tcnt, slab z.
// ---------------------------------------------------------------------------
template<int AMODE, int KS, int CH, int OUTMODE, int GX>
__global__ __launch_bounds__(512, 2)
void cgemm(const void* __restrict__ Asrc, int lda,
           const unsigned short* __restrict__ Bp, int nk32,
           int tcnt, int KK,
           const float* __restrict__ bias, void* __restrict__ Cout,
           int ldo, int O, int nO16,
           const short4* __restrict__ cidx, const float4* __restrict__ cwt)
{
    __shared__ unsigned short As[2][2][64 * ROWP];

    const int tid = threadIdx.x;
    int m0, o0, tbeg, zslab;
    if constexpr (GX > 0) {
        const int bid = blockIdx.x;
        o0 = (bid & (GX - 1)) * 128;      // bid%8 ~ XCD: same col-group per XCD
        m0 = (bid / GX) * 64;
        tbeg = 0; zslab = 0;
    } else {
        o0 = 0;
        m0 = blockIdx.y * 64;
        zslab = blockIdx.z;
        tbeg = zslab * tcnt;
    }

    // staging role: row = tid>>3 (0..63), k-octet = (tid&7)*8
    const int srow = tid >> 3;
    const int sk8  = (tid & 7) << 3;
    const int am = m0 + srow;
    const int an = am & (N_ - 1), ab = am >> 10;
    const int ay = an >> 5, ax = an & 31;

    // compute role: 8 waves 2x4, wave subtile 32x32
    const int lane = tid & 63, wid = tid >> 6;
    const int wr = (wid >> 2) * 32, wc = (wid & 3) * 32;
    const int l15 = lane & 15, lk = (lane >> 4) * 8;

    const int o16a = min((o0 + wc) >> 4, nO16 - 1);
    const int o16b = min((o0 + wc + 16) >> 4, nO16 - 1);
    const unsigned short* bbA = Bp + (size_t)o16a * nk32 * 512 + lane * 8;
    const unsigned short* bbB = Bp + (size_t)o16b * nk32 * 512 + lane * 8;

    // ---- per-tap staging state ----
    const float* fp = nullptr;                       // AMODE 0
    const unsigned short* sp = nullptr;              // AMODE 1
    bool svalid = false;
    const unsigned short *g0p = nullptr, *g1p = nullptr,
                         *g2p = nullptr, *g3p = nullptr;  // AMODE 2
    float4 scw = {0.f, 0.f, 0.f, 0.f};

    auto setShift = [&](int t) {
        const int PAD = KS / 2;
        const int ty = t / KS, tx = t - ty * KS;
        const int yy = ay + ty - PAD, xx = ax + tx - PAD;
        svalid = (yy >= 0 && yy < H_ && xx >= 0 && xx < W_);
        if (svalid)
            sp = (const unsigned short*)Asrc
               + (size_t)((ab << 10) | (yy << 5) | xx) * lda + sk8;
    };
    auto setGather = [&](short4 ci, float4 cw) {
        const unsigned short* base = (const unsigned short*)Asrc;
        g0p = base + (size_t)(int)ci.x * lda + sk8;
        g1p = base + (size_t)(int)ci.y * lda + sk8;
        g2p = base + (size_t)(int)ci.z * lda + sk8;
        g3p = base + (size_t)(int)ci.w * lda + sk8;
        scw = cw;
    };
    auto stage = [&](int s) -> uint4 {
        if constexpr (AMODE == 0) {
            const float* p = fp + (s << 6);
            const float4 v0 = *(const float4*)p;
            const float4 v1 = *(const float4*)(p + 4);
            return make_uint4(f2bf2(v0.x, v0.y), f2bf2(v0.z, v0.w),
                              f2bf2(v1.x, v1.y), f2bf2(v1.z, v1.w));
        } else if constexpr (AMODE == 1) {
            if (!svalid) return make_uint4(0u, 0u, 0u, 0u);
            return *(const uint4*)(sp + (s << 6));
        } else {
            const uint4 g0 = *(const uint4*)(g0p + (s << 6));
            const uint4 g1 = *(const uint4*)(g1p + (s << 6));
            const uint4 g2 = *(const uint4*)(g2p + (s << 6));
            const uint4 g3 = *(const uint4*)(g3p + (s << 6));
            const unsigned int* pa = (const unsigned int*)&g0;
            const unsigned int* pb = (const unsigned int*)&g1;
            const unsigned int* pc = (const unsigned int*)&g2;
            const unsigned int* pd = (const unsigned int*)&g3;
            uint4 out;
            unsigned int* po = (unsigned int*)&out;
#pragma unroll
            for (int j = 0; j < 4; ++j) {
                const float rl = scw.x * bflo(pa[j]) + scw.y * bflo(pb[j])
                               + scw.z * bflo(pc[j]) + scw.w * bflo(pd[j]);
                const float rh = scw.x * bfhi(pa[j]) + scw.y * bfhi(pb[j])
                               + scw.z * bfhi(pc[j]) + scw.w * bfhi(pd[j]);
                po[j] = f2bf2(rl, rh);
            }
            return out;
        }
    };

    // init tap state for tap tbeg
    if constexpr (AMODE == 0) fp = (const float*)Asrc + (size_t)am * lda + sk8;
    else if constexpr (AMODE == 1) setShift(tbeg);
    else setGather(cidx[(size_t)am * KK + tbeg], cwt[(size_t)am * KK + tbeg]);

    f32x4 acc[2][2];
#pragma unroll
    for (int i = 0; i < 2; ++i)
#pragma unroll
        for (int j = 0; j < 2; ++j)
            acc[i][j] = (f32x4){0.f, 0.f, 0.f, 0.f};

    // prologue: stage (t0, s0), load B (t0, s0)
    {
        const uint4 v = stage(0);
        *(uint4*)&As[0][sk8 >> 5][srow * ROWP + (sk8 & 31)] = v;
    }
    const int q00 = tbeg * (2 * CH);
    short8b cA0 = *(const short8b*)(bbA + (size_t)(q00    ) * 512);
    short8b cA1 = *(const short8b*)(bbA + (size_t)(q00 + 1) * 512);
    short8b cB0 = *(const short8b*)(bbB + (size_t)(q00    ) * 512);
    short8b cB1 = *(const short8b*)(bbB + (size_t)(q00 + 1) * 512);
    __syncthreads();

    int cur = 0;

    // one pipeline step: prefetch B(qn), stage A for next step, MFMA current.
    auto step = [&](int s, int qn, bool doNext, bool newTap, int tnext,
                    short4 cin, float4 cwn) {
        short8b nA0, nA1, nB0, nB1;
        if (doNext) {
            nA0 = *(const short8b*)(bbA + (size_t)(qn    ) * 512);
            nA1 = *(const short8b*)(bbA + (size_t)(qn + 1) * 512);
            nB0 = *(const short8b*)(bbB + (size_t)(qn    ) * 512);
            nB1 = *(const short8b*)(bbB + (size_t)(qn + 1) * 512);
        }
        uint4 nv;
        if (doNext) {
            if (newTap) {
                if constexpr (AMODE == 1) setShift(tnext);
                else if constexpr (AMODE == 2) setGather(cin, cwn);
                nv = stage(0);
            } else {
                nv = stage(s + 1);
            }
        }
        const unsigned short* a0 = As[cur][0];
        const unsigned short* a1 = As[cur][1];
        const short8b af00 = *(const short8b*)(a0 + (wr      + l15) * ROWP + lk);
        const short8b af01 = *(const short8b*)(a0 + (wr + 16 + l15) * ROWP + lk);
        const short8b af10 = *(const short8b*)(a1 + (wr      + l15) * ROWP + lk);
        const short8b af11 = *(const short8b*)(a1 + (wr + 16 + l15) * ROWP + lk);

        acc[0][0] = MFMA_(af00, cA0, acc[0][0]);
        acc[0][1] = MFMA_(af00, cB0, acc[0][1]);
        acc[1][0] = MFMA_(af01, cA0, acc[1][0]);
        acc[1][1] = MFMA_(af01, cB0, acc[1][1]);
        acc[0][0] = MFMA_(af10, cA1, acc[0][0]);
        acc[0][1] = MFMA_(af10, cB1, acc[0][1]);
        acc[1][0] = MFMA_(af11, cA1, acc[1][0]);
        acc[1][1] = MFMA_(af11, cB1, acc[1][1]);

        if (doNext)
            *(uint4*)&As[cur ^ 1][sk8 >> 5][srow * ROWP + (sk8 & 31)] = nv;
        __syncthreads();
        cur ^= 1;
        cA0 = nA0; cA1 = nA1; cB0 = nB0; cB1 = nB1;
    };

    // steady taps (next tap always exists): no runtime branches in hot path
    for (int ti = 0; ti + 1 < tcnt; ++ti) {
        short4 cin = {0, 0, 0, 0}; float4 cwn = {0.f, 0.f, 0.f, 0.f};
        if constexpr (AMODE == 2) {
            cin = cidx[(size_t)am * KK + tbeg + ti + 1];
            cwn = cwt [(size_t)am * KK + tbeg + ti + 1];
        }
        const int qt = (tbeg + ti) * (2 * CH);
        const int qn0 = (tbeg + ti + 1) * (2 * CH);
#pragma unroll
        for (int s = 0; s < CH; ++s) {
            const bool nt = (s == CH - 1);
            step(s, nt ? qn0 : qt + (s + 1) * 2, true, nt, tbeg + ti + 1, cin, cwn);
        }
    }
    // final tap
    {
        const int qt = (tbeg + tcnt - 1) * (2 * CH);
        const short4 cz = {0, 0, 0, 0}; const float4 cwz = {0.f, 0.f, 0.f, 0.f};
#pragma unroll
        for (int s = 0; s < CH; ++s)
            step(s, qt + (s + 1) * 2, s < CH - 1, false, 0, cz, cwz);
    }

    // epilogue: C/D layout col = lane&15, row = (lane>>4)*4 + r  (verified)
    const int row0 = m0 + wr + (lane >> 4) * 4;
    const int col0 = o0 + wc + l15;
#pragma unroll
    for (int j = 0; j < 2; ++j) {
        const int cc = col0 + j * 16;
        if (cc < O) {
#pragma unroll
            for (int i = 0; i < 2; ++i)
#pragma unroll
                for (int r = 0; r < 4; ++r) {
                    const int row = row0 + i * 16 + r;
                    if constexpr (OUTMODE == 0)
                        ((float*)Cout)[(size_t)row * ldo + cc] = acc[i][j][r] + bias[cc];
                    else if constexpr (OUTMODE == 1)
                        ((unsigned short*)Cout)[(size_t)row * ldo + cc] =
                            f2bf(acc[i][j][r] + bias[cc]);
                    else
                        ((float*)Cout)[(size_t)zslab * (B_ * N_) * 64
                                       + (size_t)row * 64 + cc] = acc[i][j][r];
                }
        }
    }
}

// ---------------------------------------------------------------------------
// Weight fragment-packing (verified).  src: [O][Kc][KK] (KK>1) or [O][Kc].
// dst frag: ((o16*nk32 + k32)*64 + (o&15) + ((k>>3)&3)*16)*8 + (k&7)
// ---------------------------------------------------------------------------
__global__ void pack_w(const float* __restrict__ w, unsigned short* __restrict__ dst,
                       int Ovalid, int Opad, int obase, int Kc, int KK, int t0, int Ktot)
{
    const int gid = blockIdx.x * blockDim.x + threadIdx.x;
    if (gid >= Opad * Ktot) return;
    const int k  = gid % Ktot;
    const int od = gid / Ktot;
    float v = 0.f;
    if (od < Ovalid) {
        const size_t o = obase + od;
        if (KK == 1) {
            v = w[o * Kc + k];
        } else {
            const int t = t0 + (k >> 9);
            const int c = k & 511;
            v = w[(o * Kc + c) * KK + t];
        }
    }
    const int o16 = od >> 4, l = od & 15, k32 = k >> 5;
    const size_t di = ((size_t)(o16 * (Ktot >> 5) + k32) * 64
                       + (l + ((k >> 3) & 3) * 16)) * 8 + (k & 7);
    dst[di] = f2bf(v);
}

// ---------------------------------------------------------------------------
// Bilinear coefficients; offsets arrive as Z K-split partial slabs + bias.
// offp: [Z][4096][64], dy at col 2t, dx at col 2t+1.  cidx stored short4.
// ---------------------------------------------------------------------------
template<int KS, int Z>
__global__ void coeff_kernel(const float* __restrict__ offp,
                             const float* __restrict__ ob,
                             short4* __restrict__ cidx, float4* __restrict__ cwt)
{
    const int KK = KS * KS, PAD = KS / 2;
    const int gid = blockIdx.x * blockDim.x + threadIdx.x;
    if (gid >= B_ * N_ * KK) return;
    const int t = gid % KK;
    const int n = (gid / KK) & (N_ - 1);
    const int b = gid / (KK * N_);
    const int mtok = b * N_ + n;

    const int SL = B_ * N_ * 64;
    float dy = ob[2 * t], dx = ob[2 * t + 1];
#pragma unroll
    for (int z = 0; z < Z; ++z) {
        dy += offp[(size_t)z * SL + (size_t)mtok * 64 + 2 * t];
        dx += offp[(size_t)z * SL + (size_t)mtok * 64 + 2 * t + 1];
    }

    const int y = n >> 5, x = n & 31;
    const float py = (float)(y - PAD + t / KS) + dy;
    const float px = (float)(x - PAD + t % KS) + dx;
    const float y0f = floorf(py), x0f = floorf(px);
    const float fy = py - y0f, fx = px - x0f;
    const int y0 = (int)y0f, x0 = (int)x0f;

    int idx[4]; float wt[4];
    const int   yy[4] = {y0, y0, y0 + 1, y0 + 1};
    const int   xx[4] = {x0, x0 + 1, x0, x0 + 1};
    const float ww[4] = {(1.f - fy) * (1.f - fx), (1.f - fy) * fx,
                         fy * (1.f - fx),         fy * fx};
#pragma unroll
    for (int r = 0; r < 4; ++r) {
        const bool v = (yy[r] >= 0 && yy[r] < H_ && xx[r] >= 0 && xx[r] < W_);
        const int yc = min(max(yy[r], 0), H_ - 1);
        const int xc = min(max(xx[r], 0), W_ - 1);
        idx[r] = b * N_ + yc * W_ + xc;
        wt[r] = v ? ww[r] : 0.f;
    }
    cidx[(size_t)mtok * KK + t] =
        make_short4((short)idx[0], (short)idx[1], (short)idx[2], (short)idx[3]);
    cwt[(size_t)mtok * KK + t] = make_float4(wt[0], wt[1], wt[2], wt[3]);
}

// ---------------------------------------------------------------------------
// LayerNorm + exact GELU  (verified)
// ---------------------------------------------------------------------------
__global__ __launch_bounds__(256)
void ln_gelu(float* __restrict__ ytok, const float* __restrict__ g,
             const float* __restrict__ bt)
{
    const int t = blockIdx.x;
    const int tid = threadIdx.x;
    float* row = ytok + (size_t)t * CHID_;

    float4 v = *(const float4*)&row[tid << 2];
    __shared__ float red[4];

    float s = v.x + v.y + v.z + v.w;
#pragma unroll
    for (int o = 32; o > 0; o >>= 1) s += __shfl_down(s, o, 64);
    if ((tid & 63) == 0) red[tid >> 6] = s;
    __syncthreads();
    const float mean = (red[0] + red[1] + red[2] + red[3]) * (1.f / CHID_);

    const float d0 = v.x - mean, d1 = v.y - mean, d2 = v.z - mean, d3 = v.w - mean;
    float q = d0 * d0 + d1 * d1 + d2 * d2 + d3 * d3;
#pragma unroll
    for (int o = 32; o > 0; o >>= 1) q += __shfl_down(q, o, 64);
    __syncthreads();
    if ((tid & 63) == 0) red[tid >> 6] = q;
    __syncthreads();
    const float var = (red[0] + red[1] + red[2] + red[3]) * (1.f / CHID_);
    const float rstd = rsqrtf(var + 1e-5f);

    const float4 gv = *(const float4*)&g[tid << 2];
    const float4 bv = *(const float4*)&bt[tid << 2];
    float o0 = d0 * rstd * gv.x + bv.x;
    float o1 = d1 * rstd * gv.y + bv.y;
    float o2 = d2 * rstd * gv.z + bv.z;
    float o3 = d3 * rstd * gv.w + bv.w;
    o0 = 0.5f * o0 * (1.f + erff(o0 * 0.70710678118654752f));
    o1 = 0.5f * o1 * (1.f + erff(o1 * 0.70710678118654752f));
    o2 = 0.5f * o2 * (1.f + erff(o2 * 0.70710678118654752f));
    o3 = 0.5f * o3 * (1.f + erff(o3 * 0.70710678118654752f));
    *(float4*)&row[tid << 2] = make_float4(o0, o1, o2, o3);
}

// ---------------------------------------------------------------------------
extern "C" void kernel_launch(void* const* d_in, const int* in_sizes, int n_in,
                              void* d_out, int out_size, void* d_ws, size_t ws_size,
                              hipStream_t stream) {
    const float* x       = (const float*)d_in[0];
    const float* fc1_w   = (const float*)d_in[3];
    const float* fc1_b   = (const float*)d_in[4];
    const float* off3_w  = (const float*)d_in[5];
    const float* off3_b  = (const float*)d_in[6];
    const float* conv3_w = (const float*)d_in[7];
    const float* conv3_b = (const float*)d_in[8];
    const float* off5_w  = (const float*)d_in[9];
    const float* off5_b  = (const float*)d_in[10];
    const float* conv5_w = (const float*)d_in[11];
    const float* conv5_b = (const float*)d_in[12];
    const float* ln_g    = (const float*)d_in[13];
    const float* ln_b    = (const float*)d_in[14];
    const float* fc2_w   = (const float*)d_in[15];
    const float* fc2_b   = (const float*)d_in[16];
    float* out = (float*)d_out;

    // Workspace (peak 50.17 MB <= 51.2 MB floor), with liveness overlays:
    //  ytok[0,16M): early-aliased by offp/cidx3/cwt3 (all dead before plain3)
    //  daccb overlays fc1wb/off3wb/off5wb (dead before deform3 writes daccb)
    char* ws = (char*)d_ws;
    float*          ytok   = (float*)(ws);                    // [4096][1024] fp32
    float*          offp   = (float*)(ws);                    // [<=5][4096][64]
    short4*         cidx3  = (short4*)(ws + 5242880);         //   294,912
    float4*         cwt3   = (float4*)(ws + 5537792);         //   589,824
    short4*         cidx5  = (short4*)(ws + 16777216);        //   819,200
    float4*         cwt5   = (float4*)(ws + 17596416);        // 1,638,400
    unsigned short* hb     = (unsigned short*)(ws + 19234816);// [4096][1024] bf16
    unsigned short* fc1wb  = (unsigned short*)(ws + 27623424);//   524,288
    unsigned short* off3wb = (unsigned short*)(ws + 28147712);//   589,824
    unsigned short* off5wb = (unsigned short*)(ws + 28737536);// 1,638,400
    unsigned short* daccb  = (unsigned short*)(ws + 27623424);// 4,194,304 (overlay)
    unsigned short* fc2wb  = (unsigned short*)(ws + 31817728);//   524,288
    unsigned short* conv3wb= (unsigned short*)(ws + 32342016);// 4,718,592
    unsigned short* conv5wb= (unsigned short*)(ws + 37060608);// 13,107,200 -> 50,167,808

    const dim3 TB(256);
    const dim3 TG(512);

    // ---- weight fragment-packs ----
    pack_w<<<(1024*256  + 255)/256, TB, 0, stream>>>(fc1_w,  fc1wb,  1024, 1024, 0, 256, 1, 0, 256);
    pack_w<<<(256*1024  + 255)/256, TB, 0, stream>>>(fc2_w,  fc2wb,  256,  256,  0, 1024, 1, 0, 1024);
    pack_w<<<(64*4608   + 255)/256, TB, 0, stream>>>(off3_w, off3wb, 18,   64,   0, 512, 9, 0, 4608);
    pack_w<<<(64*12800  + 255)/256, TB, 0, stream>>>(off5_w, off5wb, 50,   64,   0, 512, 25, 0, 12800);
    pack_w<<<(512*4608  + 255)/256, TB, 0, stream>>>(conv3_w, conv3wb, 512, 512, 0, 512, 9, 0, 4608);
    pack_w<<<(512*12800 + 255)/256, TB, 0, stream>>>(conv5_w, conv5wb, 512, 512, 0, 512, 25, 0, 12800);

    // ---- fc1: hb = bf16(x @ fc1_w^T + b) ----
    cgemm<0,1,4,1,8><<<8*64, TG, 0, stream>>>(
        x, CIN_, fc1wb, 8, 1, 1, fc1_b, hb, CHID_, CHID_, 64, nullptr, nullptr);

    // ---- offset convs (tap-split partials) + coeffs ----
    cgemm<1,3,8,2,0><<<dim3(1,64,3), TG, 0, stream>>>(
        hb, CHID_, off3wb, 144, 3, 1, nullptr, offp, 64, 18, 4, nullptr, nullptr);
    coeff_kernel<3,3><<<(B_*N_*9 + 255)/256, TB, 0, stream>>>(offp, off3_b, cidx3, cwt3);
    cgemm<1,5,8,2,0><<<dim3(1,64,5), TG, 0, stream>>>(
        hb + C2_, CHID_, off5wb, 400, 5, 1, nullptr, offp, 64, 50, 4, nullptr, nullptr);
    coeff_kernel<5,5><<<(B_*N_*25 + 255)/256, TB, 0, stream>>>(offp, off5_b, cidx5, cwt5);

    // ---- branch 1: deform conv3 -> daccb (bf16), plain conv3 -> ytok[:, :512] ----
    cgemm<2,3,8,1,4><<<4*64, TG, 0, stream>>>(
        hb, CHID_, conv3wb, 144, 9, 9, conv3_b, daccb, C2_, C2_, 32, cidx3, cwt3);
    cgemm<1,3,8,0,4><<<4*64, TG, 0, stream>>>(
        daccb, C2_, conv3wb, 144, 9, 1, conv3_b, ytok, CHID_, C2_, 32, nullptr, nullptr);

    // ---- branch 2: deform conv5 -> daccb (bf16), plain conv5 -> ytok[:, 512:] ----
    cgemm<2,5,8,1,4><<<4*64, TG, 0, stream>>>(
        hb + C2_, CHID_, conv5wb, 400, 25, 25, conv5_b, daccb, C2_, C2_, 32, cidx5, cwt5);
    cgemm<1,5,8,0,4><<<4*64, TG, 0, stream>>>(
        daccb, C2_, conv5wb, 400, 25, 1, conv5_b, ytok + C2_, CHID_, C2_, 32, nullptr, nullptr);

    // ---- LN + GELU, then fc2 -> fp32 out ----
    ln_gelu<<<B_*N_, TB, 0, stream>>>(ytok, ln_g, ln_b);
    cgemm<0,1,16,0,2><<<2*64, TG, 0, stream>>>(
        ytok, CHID_, fc2wb, 32, 1, 1, fc2_b, out, CIN_, CIN_, 16, nullptr, nullptr);
}